// Round 7
// baseline (618.595 us; speedup 1.0000x reference)
//
#include <hip/hip_runtime.h>
#include <hip/hip_bf16.h>
#include <math.h>

// ---------- types ----------
typedef __attribute__((ext_vector_type(8)))  __bf16 bfrag;   // MFMA A/B operand (8 bf16)
typedef __attribute__((ext_vector_type(4)))  float  f32x4;
typedef __attribute__((ext_vector_type(16))) float  f32x16;  // 32x32 MFMA C/D
typedef __attribute__((ext_vector_type(8)))  short  s16x8;
typedef __attribute__((ext_vector_type(4)))  short  s16x4;
typedef __attribute__((ext_vector_type(2)))  unsigned u32x2;
typedef __attribute__((ext_vector_type(4)))  unsigned u32x4;

__device__ __forceinline__ short f2bf(float f) {
  return (short)__builtin_bit_cast(unsigned short, (__bf16)f);
}
__device__ __forceinline__ float bf2f(short s) {
  return (float)__builtin_bit_cast(__bf16, (unsigned short)s);
}
__device__ __forceinline__ unsigned cvtpk(float lo, float hi_) {
  unsigned r;
  asm("v_cvt_pk_bf16_f32 %0, %1, %2" : "=v"(r) : "v"(lo), "v"(hi_));
  return r;
}
__device__ __forceinline__ void gll16(const void* g, void* l) {
  __builtin_amdgcn_global_load_lds((const __attribute__((address_space(1))) void*)g,
                                   (__attribute__((address_space(3))) void*)l, 16, 0, 0);
}

// ---------- f32 -> bf16 convert ----------
__global__ __launch_bounds__(256) void cvt_f32_bf16(const float* __restrict__ in,
                                                    short* __restrict__ out, int n4) {
  int i = blockIdx.x * 256 + threadIdx.x;
  if (i >= n4) return;
  f32x4 v = ((const f32x4*)in)[i];
  s16x4 o;
  o.x = f2bf(v.x); o.y = f2bf(v.y); o.z = f2bf(v.z); o.w = f2bf(v.w);
  ((s16x4*)out)[i] = o;
}

// ---------- GEMM 128x128 tile, BK=64, 2-phase free-run, 2 BLOCKS/CU ----------
// C[M][N] = A[M][K] @ B[N][K]^T, bf16 in. 4 waves (2M x 2N), 256 threads.
// LDS 64 KB -> 2 independent blocks/CU: when one block drains at a barrier,
// the other block's waves keep the MFMA pipe fed (m114 at block granularity).
// Per-wave 64x64 output; wave cols = wn*32 + jh*64 + j*16 (jh = phase half).
// Per K-tile: p0 {RD_A(8)+RD_Blo(4); STG Bhi(kt+1)->buf^1; 16 MFMA} midbar
//             p1 {RD_Bhi(4); STG A(kt+2)+Blo(kt+2)->buf; 16 MFMA} vmcnt(6) bar
// WAR: each region's last ds_read is consumed by MFMA before the barrier that
// precedes its overwrite (midbar protects p0-read regions, boundary protects
// p1-read regions). RAW: boundary vmcnt(6) drains exactly all of kt+1
// (queue 14 = [A(kt+1)4,Blo(kt+1)2,Bhi(kt+1)2 | A(kt+2)4,Blo(kt+2)2] keep 6).
// Swizzle: 16B chunk c of row r at c^(r&7); source pre-swizzled for gll16.
template<bool BF16OUT>
__global__ __launch_bounds__(256) void gemm128(const short* __restrict__ A,
                                               const short* __restrict__ B,
                                               void* __restrict__ Cv,
                                               int M, int N, int K, int NBX) {
  __shared__ __align__(16) short As[2][128 * 64];   // 2 x 16 KB
  __shared__ __align__(16) short Bs[2][128 * 64];   // 2 x 16 KB (total 64 KB)
  const int tid = threadIdx.x, lane = tid & 63, wid = tid >> 6;
  const int lr = lane & 15, lg = lane >> 4;
  const int wm = wid >> 1, wn = wid & 1;
  // bijective XCD-aware block swizzle (m204)
  const int nwg = gridDim.x, orig = blockIdx.x;
  const int qq = nwg >> 3, rr = nwg & 7, xc = orig & 7, o8 = orig >> 3;
  const int wg = (xc < rr ? xc * (qq + 1) : rr * (qq + 1) + (xc - rr) * qq) + o8;
  const int bm = (wg / NBX) << 7, bn = (wg % NBX) << 7;
  const int NT = K >> 6;
  // staging: unit = 64 rows x 64 cols (8 KB) = 2 rounds of 256 thr x 16B
  const int r0 = tid >> 3;                 // row within 32-row stripe
  const int c0 = tid & 7;
  const int csrc = c0 ^ (r0 & 7);          // inverse-swizzled 16B source chunk

#define STG(OP, OPs, boff, bb, hh, kt_)                                          \
  do {                                                                           \
    _Pragma("unroll")                                                            \
    for (int s = 0; s < 2; ++s)                                                  \
      gll16(OP + (size_t)(boff + (hh) * 64 + s * 32 + r0) * K + (kt_) * 64 + csrc * 8, \
            (char*)OPs[bb] + ((hh) * 64 + s * 32 + wid * 8) * 128);              \
  } while (0)

  int ch[2];
#pragma unroll
  for (int ks = 0; ks < 2; ++ks) ch[ks] = (((ks << 2) | lg) ^ (lr & 7)) << 4;
  const int aoff  = (wm * 64 + lr) * 128;   // A LDS byte base (row stride 128B)
  const int boff2 = (wn * 32 + lr) * 128;   // B LDS byte base

#define RD_A(dst, bb)                                                            \
  do {                                                                           \
    const char* ab = (const char*)As[bb] + aoff;                                 \
    _Pragma("unroll") for (int i = 0; i < 4; ++i)                                \
      _Pragma("unroll") for (int ks = 0; ks < 2; ++ks)                           \
        dst[i][ks] = *(const bfrag*)(ab + i * 2048 + ch[ks]);                    \
  } while (0)
#define RD_B(dst, bb, jh)                                                        \
  do {                                                                           \
    const char* bp = (const char*)Bs[bb] + boff2 + (jh) * 8192;                  \
    _Pragma("unroll") for (int j = 0; j < 2; ++j)                                \
      _Pragma("unroll") for (int ks = 0; ks < 2; ++ks)                           \
        dst[j][ks] = *(const bfrag*)(bp + j * 2048 + ch[ks]);                    \
  } while (0)
#define MFMA16(af, bf, jh)                                                       \
  do {                                                                           \
    __builtin_amdgcn_s_setprio(1);                                               \
    _Pragma("unroll") for (int i = 0; i < 4; ++i)                                \
      _Pragma("unroll") for (int j = 0; j < 2; ++j)                              \
        _Pragma("unroll") for (int ks = 0; ks < 2; ++ks)                         \
          acc[i][(jh) * 2 + j] = __builtin_amdgcn_mfma_f32_16x16x32_bf16(        \
              af[i][ks], bf[j][ks], acc[i][(jh) * 2 + j], 0, 0, 0);              \
    __builtin_amdgcn_s_setprio(0);                                               \
  } while (0)

  // ---- prologue: tile0 fully -> buf0; A(1)+Blo(1) -> buf1 ----
  STG(A, As, bm, 0, 0, 0); STG(A, As, bm, 0, 1, 0);
  STG(B, Bs, bn, 0, 0, 0); STG(B, Bs, bn, 0, 1, 0);
  if (NT > 1) {
    STG(A, As, bm, 1, 0, 1); STG(A, As, bm, 1, 1, 1);
    STG(B, Bs, bn, 1, 0, 1);
    asm volatile("s_waitcnt vmcnt(6)" ::: "memory");
  } else {
    asm volatile("s_waitcnt vmcnt(0)" ::: "memory");
  }
  __builtin_amdgcn_s_barrier();
  __builtin_amdgcn_sched_barrier(0);

  f32x4 acc[4][4] = {};
  bfrag a_[4][2], b_lo[2][2], b_hi[2][2];

  for (int kt = 0; kt < NT; ++kt) {
    const int b = kt & 1;
    // ---- p0: quad (A, B_lo); stage B_hi(kt+1) -> buf^1 ----
    RD_A(a_, b);
    RD_B(b_lo, b, 0);
    if (kt + 1 < NT) STG(B, Bs, bn, b ^ 1, 1, kt + 1);
    MFMA16(a_, b_lo, 0);
    __builtin_amdgcn_s_barrier();          // mid: all p0 reads (A, B_lo) drained
    __builtin_amdgcn_sched_barrier(0);
    // ---- p1: quad (A, B_hi); stage A(kt+2)+B_lo(kt+2) -> buf ----
    RD_B(b_hi, b, 1);
    if (kt + 2 < NT) {
      STG(A, As, bm, b, 0, kt + 2); STG(A, As, bm, b, 1, kt + 2);
      STG(B, Bs, bn, b, 0, kt + 2);
    }
    MFMA16(a_, b_hi, 1);
    // ---- boundary: kt+1 fully landed; kt+2 stays in flight ----
    if (kt + 1 < NT) {
      if (kt + 2 < NT) asm volatile("s_waitcnt vmcnt(6)" ::: "memory");
      else             asm volatile("s_waitcnt vmcnt(0)" ::: "memory");
      __builtin_amdgcn_s_barrier();
      __builtin_amdgcn_sched_barrier(0);
    }
  }
#undef STG
#undef RD_A
#undef RD_B
#undef MFMA16
  // ---- epilogue ----
  const int rb = bm + wm * 64 + lg * 4, cb = bn + wn * 32 + lr;
#pragma unroll
  for (int i = 0; i < 4; ++i)
#pragma unroll
    for (int jh = 0; jh < 2; ++jh)
#pragma unroll
      for (int j = 0; j < 2; ++j)
#pragma unroll
        for (int r = 0; r < 4; ++r) {
          size_t idx = (size_t)(rb + i * 16 + r) * N + (cb + jh * 64 + j * 16);
          if (BF16OUT) ((short*)Cv)[idx] = f2bf(acc[i][jh * 2 + j][r]);
          else         ((float*)Cv)[idx] = acc[i][jh * 2 + j][r];
        }
}

// ---------- RoPE in-place (q heads 0..31, k heads 32..39) ----------
__global__ __launch_bounds__(256) void rope_k(short* __restrict__ qkv,
                                              const float* __restrict__ fcos,
                                              const float* __restrict__ fsin) {
  const int t = blockIdx.x;
  const int s = t & 2047;
  unsigned* row = (unsigned*)(qkv + (size_t)t * 6144);
  for (int p = threadIdx.x; p < 2560; p += 256) {
    const int h = p >> 6, i = p & 63;
    const int w = h * 64 + i;
    unsigned u = row[w];
    float a  = bf2f((short)(u & 0xffff));
    float b  = bf2f((short)(u >> 16));
    float c  = fcos[s * 64 + i], sn = fsin[s * 64 + i];
    float na = a * c - b * sn;
    float nb = a * sn + b * c;
    row[w] = ((unsigned)(unsigned short)f2bf(na)) |
             (((unsigned)(unsigned short)f2bf(nb)) << 16);
  }
}

// ---------- V transpose: qkv V-part [t][d] -> vt[b][kvh][d][s] ----------
__global__ __launch_bounds__(256) void vtrans(const short* __restrict__ qkv,
                                              short* __restrict__ vt) {
  const int sb = blockIdx.x, kvh = blockIdx.y, b = blockIdx.z;
  __shared__ short T[64][136];
  const int tid = threadIdx.x;
#pragma unroll
  for (int it = 0; it < 4; ++it) {
    int c = it * 256 + tid;
    int r = c >> 4, dc = c & 15;
    s16x8 v = *(const s16x8*)(qkv + (size_t)(b * 2048 + sb * 64 + r) * 6144
                              + 5120 + kvh * 128 + dc * 8);
    *(s16x8*)&T[r][dc * 8] = v;
  }
  __syncthreads();
#pragma unroll
  for (int it = 0; it < 4; ++it) {
    int c = it * 256 + tid;
    int d = c >> 3, sc = c & 7;
    s16x8 v;
#pragma unroll
    for (int j = 0; j < 8; ++j) v[j] = T[sc * 8 + j][d];
    *(s16x8*)(vt + (size_t)((b * 8 + kvh) * 128 + d) * 2048 + sb * 64 + sc * 8) = v;
  }
}

// ---------- Flash attention, m214 structure (unchanged) ----------
__global__ __launch_bounds__(512, 2) void fattn2(const short* __restrict__ qkv,
                                                 const short* __restrict__ vt,
                                                 short* __restrict__ ao) {
  const int qb = blockIdx.x, h = blockIdx.y, b = blockIdx.z;
  const int kvh = h >> 2;
  const int tid = threadIdx.x;
  const int lane = tid & 63, wid = tid >> 6;
  const int l31 = lane & 31, hi = lane >> 5;
  __shared__ __align__(16) short Ks[2][64 * 128];
  __shared__ __align__(16) short Vs[2][128 * 64];

  const int q0w   = qb * 256 + wid * 32;
  const int qg    = q0w + l31;
  const int tmaxw = q0w >> 6;
  const int NT    = 4 * qb + 4;

  bfrag qf[8];
  {
    const short* qp = qkv + (size_t)(b * 2048 + qg) * 6144 + h * 128 + hi * 8;
#pragma unroll
    for (int kk = 0; kk < 8; ++kk) qf[kk] = *(const bfrag*)(qp + kk * 16);
  }

  const int kr0 = tid >> 4, kcc = tid & 15;
  const int vd0 = tid >> 3, vkc = tid & 7;
  const int kro[2] = { kr0, kr0 + 32 };
  const int vdo[2] = { vd0, vd0 + 64 };
  int kldst[2], vldst[2];
#pragma unroll
  for (int i = 0; i < 2; ++i) {
    kldst[i] = (kro[i] * 256 + kcc * 16) ^ ((kro[i] & 7) << 4);
    vldst[i] = (vdo[i] * 128 + vkc * 16) ^ ((vdo[i] & 7) << 4);
  }
  const short* base_k = qkv + (size_t)(b * 2048) * 6144 + 4096 + kvh * 128;
  const short* base_v = vt + (size_t)((b * 8 + kvh) * 128) * 2048;

  {
    s16x8 kr_[2], vr_[2];
#pragma unroll
    for (int i = 0; i < 2; ++i) {
      kr_[i] = *(const s16x8*)(base_k + (size_t)kro[i] * 6144 + kcc * 8);
      vr_[i] = *(const s16x8*)(base_v + (size_t)vdo[i] * 2048 + vkc * 8);
    }
#pragma unroll
    for (int i = 0; i < 2; ++i) {
      *(s16x8*)((char*)Ks[0] + kldst[i]) = kr_[i];
      *(s16x8*)((char*)Vs[0] + vldst[i]) = vr_[i];
    }
  }
  __syncthreads();

  f32x16 o[4] = {};
  float m = -3.0e38f, l = 0.f;
  const float c0 = 0.08838834764831845f * 1.4426950408889634f;
  const int  sw = (l31 & 7) << 4;

  for (int t = 0; t < NT; ++t) {
    const int cur = t & 1;
    s16x8 kr_[2], vr_[2];
    const bool pf = (t + 1 < NT);
    if (pf) {
#pragma unroll
      for (int i = 0; i < 2; ++i) {
        kr_[i] = *(const s16x8*)(base_k + (size_t)((t + 1) * 64 + kro[i]) * 6144 + kcc * 8);
        vr_[i] = *(const s16x8*)(base_v + (size_t)vdo[i] * 2048 + (t + 1) * 64 + vkc * 8);
      }
    }
    if (t <= tmaxw) {
      f32x16 st[2];
      __builtin_amdgcn_s_setprio(1);
#pragma unroll
      for (int kt = 0; kt < 2; ++kt) {
        f32x16 acc = {};
        const char* kb = (const char*)Ks[cur] + kt * 8192 + l31 * 256;
#pragma unroll
        for (int kk = 0; kk < 8; ++kk) {
          bfrag kf = *(const bfrag*)(kb + ((kk * 32 + hi * 16) ^ sw));
          acc = __builtin_amdgcn_mfma_f32_32x32x16_bf16(kf, qf[kk], acc, 0, 0, 0);
        }
        st[kt] = acc;
      }
      __builtin_amdgcn_s_setprio(0);
      if (t == tmaxw) {
        const int kb0 = t * 64 + 4 * hi;
#pragma unroll
        for (int kt = 0; kt < 2; ++kt)
#pragma unroll
          for (int r = 0; r < 16; ++r) {
            int k = kb0 + kt * 32 + (r & 3) + 8 * (r >> 2);
            if (k > qg) st[kt][r] = -3.0e38f;
          }
      }
      float mt = -3.0e38f;
#pragma unroll
      for (int kt = 0; kt < 2; ++kt)
#pragma unroll
        for (int r = 0; r < 16; ++r) mt = fmaxf(mt, st[kt][r]);
      mt = fmaxf(mt, __shfl_xor(mt, 32, 64));
      if (!__all((mt - m) * c0 <= 8.0f)) {
        float nm = fmaxf(m, mt);
        float fe = exp2f((m - nm) * c0);
        m = nm;
        l *= fe;
#pragma unroll
        for (int dt = 0; dt < 4; ++dt)
#pragma unroll
          for (int r = 0; r < 16; ++r) o[dt][r] *= fe;
      }
      const float mc = m * c0;
      float ps = 0.f;
#pragma unroll
      for (int kt = 0; kt < 2; ++kt)
#pragma unroll
        for (int r = 0; r < 16; ++r) {
          float p = exp2f(st[kt][r] * c0 - mc);
          st[kt][r] = p;
          ps += p;
        }
      ps += __shfl_xor(ps, 32, 64);
      l += ps;
      bfrag pfr[4];
#pragma unroll
      for (int kt = 0; kt < 2; ++kt) {
        u32x2 a0 = __builtin_amdgcn_permlane32_swap(cvtpk(st[kt][0],  st[kt][1]),
                                                    cvtpk(st[kt][4],  st[kt][5]),  0, 0);
        u32x2 a1 = __builtin_amdgcn_permlane32_swap(cvtpk(st[kt][2],  st[kt][3]),
                                                    cvtpk(st[kt][6],  st[kt][7]),  0, 0);
        u32x2 b0 = __builtin_amdgcn_permlane32_swap(cvtpk(st[kt][8],  st[kt][9]),
                                                    cvtpk(st[kt][12], st[kt][13]), 0, 0);
        u32x2 b1 = __builtin_amdgcn_permlane32_swap(cvtpk(st[kt][10], st[kt][11]),
                                                    cvtpk(st[kt][14], st[kt][15]), 0, 0);
        u32x4 w0 = { a0.x, a1.x, a0.y, a1.y };
        u32x4 w1 = { b0.x, b1.x, b0.y, b1.y };
        pfr[kt * 2]     = __builtin_bit_cast(bfrag, w0);
        pfr[kt * 2 + 1] = __builtin_bit_cast(bfrag, w1);
      }
      __builtin_amdgcn_s_setprio(1);
#pragma unroll
      for (int ks = 0; ks < 4; ++ks) {
        const char* vb = (const char*)Vs[cur] + l31 * 128 + ((ks * 32 + hi * 16) ^ sw);
#pragma unroll
        for (int dt = 0; dt < 4; ++dt) {
          bfrag vf = *(const bfrag*)(vb + dt * 4096);
          o[dt] = __builtin_amdgcn_mfma_f32_32x32x16_bf16(vf, pfr[ks], o[dt], 0, 0, 0);
        }
      }
      __builtin_amdgcn_s_setprio(0);
    }
    __syncthreads();
    if (pf) {
#pragma unroll
      for (int i = 0; i < 2; ++i) {
        *(s16x8*)((char*)Ks[cur ^ 1] + kldst[i]) = kr_[i];
        *(s16x8*)((char*)Vs[cur ^ 1] + vldst[i]) = vr_[i];
      }
    }
    __syncthreads();
  }
  const float linv = 1.f / l;
  short* aop = ao + (size_t)(b * 2048 + qg) * 4096 + h * 128 + 4 * hi;
#pragma unroll
  for (int dt = 0; dt < 4; ++dt)
#pragma unroll
    for (int r = 0; r < 16; ++r) {
      int d = dt * 32 + (r & 3) + 8 * (r >> 2);
      aop[d] = f2bf(o[dt][r] * linv);
    }
}

// ---------- launch ----------
extern "C" void kernel_launch(void* const* d_in, const int* in_sizes, int n_in,
                              void* d_out, int out_size, void* d_ws, size_t ws_size,
                              hipStream_t stream) {
  const float* x  = (const float*)d_in[0];
  const float* wq = (const float*)d_in[1];
  const float* wk = (const float*)d_in[2];
  const float* wv = (const float*)d_in[3];
  const float* wo = (const float*)d_in[4];
  const float* fc = (const float*)d_in[7];
  const float* fs = (const float*)d_in[8];

  char* ws = (char*)d_ws;
  short* xb    = (short*)(ws);                    // [4096][4096] bf16; reused as ao
  short* ao    = xb;
  short* wqkvb = (short*)(ws + 33554432ull);      // [6144][4096] bf16; reused as wob
  short* wob   = wqkvb;
  short* qkv   = (short*)(ws + 83886080ull);      // [4096][6144] bf16
  short* vt    = (short*)(ws + 134217728ull);     // [2][8][128][2048] bf16

  cvt_f32_bf16<<<16384, 256, 0, stream>>>(x,  xb,                 4194304);
  cvt_f32_bf16<<<16384, 256, 0, stream>>>(wq, wqkvb,              4194304);
  cvt_f32_bf16<<< 4096, 256, 0, stream>>>(wk, wqkvb + 16777216,   1048576);
  cvt_f32_bf16<<< 4096, 256, 0, stream>>>(wv, wqkvb + 20971520,   1048576);
  gemm128<true ><<<1536, 256, 0, stream>>>(xb, wqkvb, qkv, 4096, 6144, 4096, 48);
  rope_k<<<4096, 256, 0, stream>>>(qkv, fc, fs);
  vtrans<<<dim3(32, 8, 2), 256, 0, stream>>>(qkv, vt);
  fattn2<<<dim3(8, 32, 2), 512, 0, stream>>>(qkv, vt, ao);
  cvt_f32_bf16<<<16384, 256, 0, stream>>>(wo, wob,                4194304);
  gemm128<false><<<1024, 256, 0, stream>>>(ao, wob, (float*)d_out, 4096, 4096, 4096, 32);
}

// Round 8
// 584.745 us; speedup vs baseline: 1.0579x; 1.0579x over previous
//
#include <hip/hip_runtime.h>
#include <hip/hip_bf16.h>
#include <math.h>

// ---------- types ----------
typedef __attribute__((ext_vector_type(8)))  __bf16 bfrag;   // MFMA A/B operand (8 bf16)
typedef __attribute__((ext_vector_type(4)))  float  f32x4;
typedef __attribute__((ext_vector_type(16))) float  f32x16;  // 32x32 MFMA C/D
typedef __attribute__((ext_vector_type(8)))  short  s16x8;
typedef __attribute__((ext_vector_type(4)))  short  s16x4;
typedef __attribute__((ext_vector_type(2)))  unsigned u32x2;
typedef __attribute__((ext_vector_type(4)))  unsigned u32x4;

__device__ __forceinline__ short f2bf(float f) {
  return (short)__builtin_bit_cast(unsigned short, (__bf16)f);
}
__device__ __forceinline__ float bf2f(short s) {
  return (float)__builtin_bit_cast(__bf16, (unsigned short)s);
}
__device__ __forceinline__ unsigned cvtpk(float lo, float hi_) {
  unsigned r;
  asm("v_cvt_pk_bf16_f32 %0, %1, %2" : "=v"(r) : "v"(lo), "v"(hi_));
  return r;
}
__device__ __forceinline__ void gll16(const void* g, void* l) {
  __builtin_amdgcn_global_load_lds((const __attribute__((address_space(1))) void*)g,
                                   (__attribute__((address_space(3))) void*)l, 16, 0, 0);
}

// ---------- f32 -> bf16 converts ----------
__global__ __launch_bounds__(256) void cvt_f32_bf16(const float* __restrict__ in,
                                                    short* __restrict__ out, int n4) {
  int i = blockIdx.x * 256 + threadIdx.x;
  if (i >= n4) return;
  f32x4 v = ((const f32x4*)in)[i];
  s16x4 o;
  o.x = f2bf(v.x); o.y = f2bf(v.y); o.z = f2bf(v.z); o.w = f2bf(v.w);
  ((s16x4*)out)[i] = o;
}

// merged x|wq|wk|wv convert (one launch, 40960 blocks)
__global__ __launch_bounds__(256) void cvt4(const float* __restrict__ x,
                                            const float* __restrict__ wq,
                                            const float* __restrict__ wk,
                                            const float* __restrict__ wv,
                                            short* __restrict__ xb,
                                            short* __restrict__ wqb,
                                            short* __restrict__ wkb,
                                            short* __restrict__ wvb) {
  const int b = blockIdx.x;
  const float* in; short* out; int base;
  if (b < 16384)      { in = x;  out = xb;  base = 0; }
  else if (b < 32768) { in = wq; out = wqb; base = 16384 * 256; }
  else if (b < 36864) { in = wk; out = wkb; base = 32768 * 256; }
  else                { in = wv; out = wvb; base = 36864 * 256; }
  const int idx = b * 256 + threadIdx.x - base;
  f32x4 v = ((const f32x4*)in)[idx];
  s16x4 o;
  o.x = f2bf(v.x); o.y = f2bf(v.y); o.z = f2bf(v.z); o.w = f2bf(v.w);
  ((s16x4*)out)[idx] = o;
}

// ---------- GEMM 128x256 tile, BK=64, 2-phase free-run, zero grid tail ----------
// C[M][N] = A[M][K] @ B[N][K]^T, bf16 in. 8 waves (2M x 4N), 512 threads.
// MFMA bursts ks-OUTERMOST: each acc[i][j]'s dependent (ks0,ks1) pair is
// separated by 8 independent MFMAs -> no accumulator RAW stalls.
// Per K-tile: p0 {RD_A(8)+RD_Blo(4); STG Bhi(kt+1)->buf^1; 16 MFMA} midbar
//             p1 {RD_Bhi(4); STG A(kt+2)+Blo(kt+2)->buf; 16 MFMA} vmcnt(4) bar
template<bool BF16OUT>
__global__ __launch_bounds__(512) void gemm128n(const short* __restrict__ A,
                                                const short* __restrict__ B,
                                                void* __restrict__ Cv,
                                                int M, int N, int K, int NBX) {
  __shared__ __align__(16) short As[2][128 * 64];   // 2 x 16 KB
  __shared__ __align__(16) short Bs[2][256 * 64];   // 2 x 32 KB (total 96 KB)
  const int tid = threadIdx.x, lane = tid & 63, wid = tid >> 6;
  const int lr = lane & 15, lg = lane >> 4;
  const int wm = wid >> 2, wn = wid & 3;
  // bijective XCD-aware block swizzle (m204)
  const int nwg = gridDim.x, orig = blockIdx.x;
  const int qq = nwg >> 3, rr = nwg & 7, xc = orig & 7, o8 = orig >> 3;
  const int wg = (xc < rr ? xc * (qq + 1) : rr * (qq + 1) + (xc - rr) * qq) + o8;
  const int bm = (wg / NBX) << 7, bn = (wg % NBX) << 8;
  const int NT = K >> 6;
  const int r0 = tid >> 3;                 // row within 64-row stripe
  const int c0 = tid & 7;
  const int csrc = c0 ^ (r0 & 7);          // inverse-swizzled 16B source chunk

#define STG(OP, OPs, boff, bb, hh, kt_)                                          \
  do {                                                                           \
    _Pragma("unroll")                                                            \
    for (int s = 0; s < 2; ++s)                                                  \
      gll16(OP + (size_t)(boff + (hh) * 128 + s * 64 + r0) * K + (kt_) * 64 + csrc * 8, \
            (char*)OPs[bb] + ((hh) * 128 + s * 64 + wid * 8) * 128);             \
  } while (0)

  int ch[2];
#pragma unroll
  for (int ks = 0; ks < 2; ++ks) ch[ks] = (((ks << 2) | lg) ^ (lr & 7)) << 4;
  const int aoff  = (wm * 64 + lr) * 128;   // A LDS byte base (row stride 128B)
  const int boff2 = (wn * 32 + lr) * 128;   // B LDS byte base

#define RD_A(dst, bb)                                                            \
  do {                                                                           \
    const char* ab = (const char*)As[bb] + aoff;                                 \
    _Pragma("unroll") for (int i = 0; i < 4; ++i)                                \
      _Pragma("unroll") for (int ks = 0; ks < 2; ++ks)                           \
        dst[i][ks] = *(const bfrag*)(ab + i * 2048 + ch[ks]);                    \
  } while (0)
#define RD_B(dst, bb, jh)                                                        \
  do {                                                                           \
    const char* bp = (const char*)Bs[bb] + boff2 + (jh) * 16384;                 \
    _Pragma("unroll") for (int j = 0; j < 2; ++j)                                \
      _Pragma("unroll") for (int ks = 0; ks < 2; ++ks)                           \
        dst[j][ks] = *(const bfrag*)(bp + j * 2048 + ch[ks]);                    \
  } while (0)
// ks OUTERMOST: dependent pairs on each acc separated by 8 independent MFMAs
#define MFMA16(af, bf, jh)                                                       \
  do {                                                                           \
    __builtin_amdgcn_s_setprio(1);                                               \
    _Pragma("unroll") for (int ks = 0; ks < 2; ++ks)                             \
      _Pragma("unroll") for (int i = 0; i < 4; ++i)                              \
        _Pragma("unroll") for (int j = 0; j < 2; ++j)                            \
          acc[i][(jh) * 2 + j] = __builtin_amdgcn_mfma_f32_16x16x32_bf16(        \
              af[i][ks], bf[j][ks], acc[i][(jh) * 2 + j], 0, 0, 0);              \
    __builtin_amdgcn_s_setprio(0);                                               \
  } while (0)

  // ---- prologue: A(0), Blo(0), Bhi(0) -> buf0; A(1), Blo(1) -> buf1 ----
  STG(A, As, bm, 0, 0, 0);
  STG(B, Bs, bn, 0, 0, 0);
  STG(B, Bs, bn, 0, 1, 0);
  if (NT > 1) {
    STG(A, As, bm, 1, 0, 1);
    STG(B, Bs, bn, 1, 0, 1);
    asm volatile("s_waitcnt vmcnt(4)" ::: "memory");
  } else {
    asm volatile("s_waitcnt vmcnt(0)" ::: "memory");
  }
  __builtin_amdgcn_s_barrier();
  __builtin_amdgcn_sched_barrier(0);

  f32x4 acc[4][4] = {};
  bfrag a_[4][2], b_lo[2][2], b_hi[2][2];

  for (int kt = 0; kt < NT; ++kt) {
    const int b = kt & 1;
    // ---- p0: quad (A, B_lo); stage B_hi(kt+1) -> buf^1 ----
    RD_A(a_, b);
    RD_B(b_lo, b, 0);
    if (kt + 1 < NT) STG(B, Bs, bn, b ^ 1, 1, kt + 1);
    MFMA16(a_, b_lo, 0);
    __builtin_amdgcn_s_barrier();          // mid: A(kt)/Blo(kt) reads drained by MFMA
    __builtin_amdgcn_sched_barrier(0);
    // ---- p1: quad (A, B_hi); stage A(kt+2), B_lo(kt+2) -> buf ----
    RD_B(b_hi, b, 1);
    if (kt + 2 < NT) {
      STG(A, As, bm, b, 0, kt + 2);
      STG(B, Bs, bn, b, 0, kt + 2);
    }
    MFMA16(a_, b_hi, 1);
    // ---- boundary: kt+1 fully landed; kt+2 stays in flight ----
    if (kt + 1 < NT) {
      if (kt + 2 < NT) asm volatile("s_waitcnt vmcnt(4)" ::: "memory");
      else             asm volatile("s_waitcnt vmcnt(0)" ::: "memory");
      __builtin_amdgcn_s_barrier();
      __builtin_amdgcn_sched_barrier(0);
    }
  }
#undef STG
#undef RD_A
#undef RD_B
#undef MFMA16
  // ---- epilogue ----
  const int rb = bm + wm * 64 + lg * 4, cb = bn + wn * 32 + lr;
#pragma unroll
  for (int i = 0; i < 4; ++i)
#pragma unroll
    for (int jh = 0; jh < 2; ++jh)
#pragma unroll
      for (int j = 0; j < 2; ++j)
#pragma unroll
        for (int r = 0; r < 4; ++r) {
          size_t idx = (size_t)(rb + i * 16 + r) * N + (cb + jh * 128 + j * 16);
          if (BF16OUT) ((short*)Cv)[idx] = f2bf(acc[i][jh * 2 + j][r]);
          else         ((float*)Cv)[idx] = acc[i][jh * 2 + j][r];
        }
}

// ---------- RoPE in-place (q heads 0..31, k heads 32..39) ----------
__global__ __launch_bounds__(256) void rope_k(short* __restrict__ qkv,
                                              const float* __restrict__ fcos,
                                              const float* __restrict__ fsin) {
  const int t = blockIdx.x;
  const int s = t & 2047;
  unsigned* row = (unsigned*)(qkv + (size_t)t * 6144);
  for (int p = threadIdx.x; p < 2560; p += 256) {
    const int h = p >> 6, i = p & 63;
    const int w = h * 64 + i;
    unsigned u = row[w];
    float a  = bf2f((short)(u & 0xffff));
    float b  = bf2f((short)(u >> 16));
    float c  = fcos[s * 64 + i], sn = fsin[s * 64 + i];
    float na = a * c - b * sn;
    float nb = a * sn + b * c;
    row[w] = ((unsigned)(unsigned short)f2bf(na)) |
             (((unsigned)(unsigned short)f2bf(nb)) << 16);
  }
}

// ---------- V transpose: qkv V-part [t][d] -> vt[b][kvh][d][s] ----------
__global__ __launch_bounds__(256) void vtrans(const short* __restrict__ qkv,
                                              short* __restrict__ vt) {
  const int sb = blockIdx.x, kvh = blockIdx.y, b = blockIdx.z;
  __shared__ short T[64][136];
  const int tid = threadIdx.x;
#pragma unroll
  for (int it = 0; it < 4; ++it) {
    int c = it * 256 + tid;
    int r = c >> 4, dc = c & 15;
    s16x8 v = *(const s16x8*)(qkv + (size_t)(b * 2048 + sb * 64 + r) * 6144
                              + 5120 + kvh * 128 + dc * 8);
    *(s16x8*)&T[r][dc * 8] = v;
  }
  __syncthreads();
#pragma unroll
  for (int it = 0; it < 4; ++it) {
    int c = it * 256 + tid;
    int d = c >> 3, sc = c & 7;
    s16x8 v;
#pragma unroll
    for (int j = 0; j < 8; ++j) v[j] = T[sc * 8 + j][d];
    *(s16x8*)(vt + (size_t)((b * 8 + kvh) * 128 + d) * 2048 + sb * 64 + sc * 8) = v;
  }
}

// ---------- Flash attention, m214 structure; QK chains interleaved ----------
__global__ __launch_bounds__(512, 2) void fattn2(const short* __restrict__ qkv,
                                                 const short* __restrict__ vt,
                                                 short* __restrict__ ao) {
  const int qb = blockIdx.x, h = blockIdx.y, b = blockIdx.z;
  const int kvh = h >> 2;
  const int tid = threadIdx.x;
  const int lane = tid & 63, wid = tid >> 6;
  const int l31 = lane & 31, hi = lane >> 5;
  __shared__ __align__(16) short Ks[2][64 * 128];
  __shared__ __align__(16) short Vs[2][128 * 64];

  const int q0w   = qb * 256 + wid * 32;
  const int qg    = q0w + l31;
  const int tmaxw = q0w >> 6;
  const int NT    = 4 * qb + 4;

  bfrag qf[8];
  {
    const short* qp = qkv + (size_t)(b * 2048 + qg) * 6144 + h * 128 + hi * 8;
#pragma unroll
    for (int kk = 0; kk < 8; ++kk) qf[kk] = *(const bfrag*)(qp + kk * 16);
  }

  const int kr0 = tid >> 4, kcc = tid & 15;
  const int vd0 = tid >> 3, vkc = tid & 7;
  const int kro[2] = { kr0, kr0 + 32 };
  const int vdo[2] = { vd0, vd0 + 64 };
  int kldst[2], vldst[2];
#pragma unroll
  for (int i = 0; i < 2; ++i) {
    kldst[i] = (kro[i] * 256 + kcc * 16) ^ ((kro[i] & 7) << 4);
    vldst[i] = (vdo[i] * 128 + vkc * 16) ^ ((vdo[i] & 7) << 4);
  }
  const short* base_k = qkv + (size_t)(b * 2048) * 6144 + 4096 + kvh * 128;
  const short* base_v = vt + (size_t)((b * 8 + kvh) * 128) * 2048;

  {
    s16x8 kr_[2], vr_[2];
#pragma unroll
    for (int i = 0; i < 2; ++i) {
      kr_[i] = *(const s16x8*)(base_k + (size_t)kro[i] * 6144 + kcc * 8);
      vr_[i] = *(const s16x8*)(base_v + (size_t)vdo[i] * 2048 + vkc * 8);
    }
#pragma unroll
    for (int i = 0; i < 2; ++i) {
      *(s16x8*)((char*)Ks[0] + kldst[i]) = kr_[i];
      *(s16x8*)((char*)Vs[0] + vldst[i]) = vr_[i];
    }
  }
  __syncthreads();

  f32x16 o[4] = {};
  float m = -3.0e38f, l = 0.f;
  const float c0 = 0.08838834764831845f * 1.4426950408889634f;
  const int  sw = (l31 & 7) << 4;

  for (int t = 0; t < NT; ++t) {
    const int cur = t & 1;
    s16x8 kr_[2], vr_[2];
    const bool pf = (t + 1 < NT);
    if (pf) {
#pragma unroll
      for (int i = 0; i < 2; ++i) {
        kr_[i] = *(const s16x8*)(base_k + (size_t)((t + 1) * 64 + kro[i]) * 6144 + kcc * 8);
        vr_[i] = *(const s16x8*)(base_v + (size_t)vdo[i] * 2048 + (t + 1) * 64 + vkc * 8);
      }
    }
    if (t <= tmaxw) {
      // ---- S^T = K @ Q : two chains interleaved (kk outer) ----
      f32x16 st[2] = {};
      {
        const char* kb = (const char*)Ks[cur] + l31 * 256;
        __builtin_amdgcn_s_setprio(1);
#pragma unroll
        for (int kk = 0; kk < 8; ++kk) {
          const int ko = (kk * 32 + hi * 16) ^ sw;
          bfrag kf0 = *(const bfrag*)(kb + ko);
          bfrag kf1 = *(const bfrag*)(kb + 8192 + ko);
          st[0] = __builtin_amdgcn_mfma_f32_32x32x16_bf16(kf0, qf[kk], st[0], 0, 0, 0);
          st[1] = __builtin_amdgcn_mfma_f32_32x32x16_bf16(kf1, qf[kk], st[1], 0, 0, 0);
        }
        __builtin_amdgcn_s_setprio(0);
      }
      if (t == tmaxw) {
        const int kb0 = t * 64 + 4 * hi;
#pragma unroll
        for (int kt = 0; kt < 2; ++kt)
#pragma unroll
          for (int r = 0; r < 16; ++r) {
            int k = kb0 + kt * 32 + (r & 3) + 8 * (r >> 2);
            if (k > qg) st[kt][r] = -3.0e38f;
          }
      }
      float mt = -3.0e38f;
#pragma unroll
      for (int kt = 0; kt < 2; ++kt)
#pragma unroll
        for (int r = 0; r < 16; ++r) mt = fmaxf(mt, st[kt][r]);
      mt = fmaxf(mt, __shfl_xor(mt, 32, 64));
      if (!__all((mt - m) * c0 <= 8.0f)) {
        float nm = fmaxf(m, mt);
        float fe = exp2f((m - nm) * c0);
        m = nm;
        l *= fe;
#pragma unroll
        for (int dt = 0; dt < 4; ++dt)
#pragma unroll
          for (int r = 0; r < 16; ++r) o[dt][r] *= fe;
      }
      const float mc = m * c0;
      float ps = 0.f;
#pragma unroll
      for (int kt = 0; kt < 2; ++kt)
#pragma unroll
        for (int r = 0; r < 16; ++r) {
          float p = exp2f(st[kt][r] * c0 - mc);
          st[kt][r] = p;
          ps += p;
        }
      ps += __shfl_xor(ps, 32, 64);
      l += ps;
      bfrag pfr[4];
#pragma unroll
      for (int kt = 0; kt < 2; ++kt) {
        u32x2 a0 = __builtin_amdgcn_permlane32_swap(cvtpk(st[kt][0],  st[kt][1]),
                                                    cvtpk(st[kt][4],  st[kt][5]),  0, 0);
        u32x2 a1 = __builtin_amdgcn_permlane32_swap(cvtpk(st[kt][2],  st[kt][3]),
                                                    cvtpk(st[kt][6],  st[kt][7]),  0, 0);
        u32x2 b0 = __builtin_amdgcn_permlane32_swap(cvtpk(st[kt][8],  st[kt][9]),
                                                    cvtpk(st[kt][12], st[kt][13]), 0, 0);
        u32x2 b1 = __builtin_amdgcn_permlane32_swap(cvtpk(st[kt][10], st[kt][11]),
                                                    cvtpk(st[kt][14], st[kt][15]), 0, 0);
        u32x4 w0 = { a0.x, a1.x, a0.y, a1.y };
        u32x4 w1 = { b0.x, b1.x, b0.y, b1.y };
        pfr[kt * 2]     = __builtin_bit_cast(bfrag, w0);
        pfr[kt * 2 + 1] = __builtin_bit_cast(bfrag, w1);
      }
      __builtin_amdgcn_s_setprio(1);
#pragma unroll
      for (int ks = 0; ks < 4; ++ks) {
        const char* vb = (const char*)Vs[cur] + l31 * 128 + ((ks * 32 + hi * 16) ^ sw);
#pragma unroll
        for (int dt = 0; dt < 4; ++dt) {
          bfrag vf = *(const bfrag*)(vb + dt * 4096);
          o[dt] = __builtin_amdgcn_mfma_f32_32x32x16_bf16(vf, pfr[ks], o[dt], 0, 0, 0);
        }
      }
      __builtin_amdgcn_s_setprio(0);
    }
    __syncthreads();
    if (pf) {
#pragma unroll
      for (int i = 0; i < 2; ++i) {
        *(s16x8*)((char*)Ks[cur ^ 1] + kldst[i]) = kr_[i];
        *(s16x8*)((char*)Vs[cur ^ 1] + vldst[i]) = vr_[i];
      }
    }
    __syncthreads();
  }
  const float linv = 1.f / l;
  short* aop = ao + (size_t)(b * 2048 + qg) * 4096 + h * 128 + 4 * hi;
#pragma unroll
  for (int dt = 0; dt < 4; ++dt)
#pragma unroll
    for (int r = 0; r < 16; ++r) {
      int d = dt * 32 + (r & 3) + 8 * (r >> 2);
      aop[d] = f2bf(o[dt][r] * linv);
    }
}

// ---------- launch ----------
extern "C" void kernel_launch(void* const* d_in, const int* in_sizes, int n_in,
                              void* d_out, int out_size, void* d_ws, size_t ws_size,
                              hipStream_t stream) {
  const float* x  = (const float*)d_in[0];
  const float* wq = (const float*)d_in[1];
  const float* wk = (const float*)d_in[2];
  const float* wv = (const float*)d_in[3];
  const float* wo = (const float*)d_in[4];
  const float* fc = (const float*)d_in[7];
  const float* fs = (const float*)d_in[8];

  char* ws = (char*)d_ws;
  short* xb    = (short*)(ws);                    // [4096][4096] bf16; reused as ao
  short* ao    = xb;
  short* wqkvb = (short*)(ws + 33554432ull);      // [6144][4096] bf16; reused as wob
  short* wob   = wqkvb;
  short* qkv   = (short*)(ws + 83886080ull);      // [4096][6144] bf16
  short* vt    = (short*)(ws + 134217728ull);     // [2][8][128][2048] bf16

  cvt4<<<40960, 256, 0, stream>>>(x, wq, wk, wv,
                                  xb, wqkvb, wqkvb + 16777216, wqkvb + 20971520);
  gemm128n<true ><<<768, 512, 0, stream>>>(xb, wqkvb, qkv, 4096, 6144, 4096, 24);
  rope_k<<<4096, 256, 0, stream>>>(qkv, fc, fs);
  vtrans<<<dim3(32, 8, 2), 256, 0, stream>>>(qkv, vt);
  cvt_f32_bf16<<<16384, 256, 0, stream>>>(wo, wob, 4194304);
  fattn2<<<dim3(8, 32, 2), 512, 0, stream>>>(qkv, vt, ao);
  gemm128n<false><<<512, 512, 0, stream>>>(ao, wob, (float*)d_out, 4096, 4096, 4096, 16);
}